// Round 6
// baseline (187.524 us; speedup 1.0000x reference)
//
#include <hip/hip_runtime.h>
#include <math.h>

// SpiralNet bf16-MFMA v6.
// vs R5: attack gather LATENCY via guaranteed memory-level parallelism.
// - Each wave preloads ALL A-fragments of a chunk (12 independent 16B gathers)
//   into registers back-to-back BEFORE any MFMA -> 12 outstanding misses/wave
//   by construction; 12 waves/CU -> ~144 outstanding/CU (Little's law needs ~32).
// - block=128 (2 waves) -> grid 1563 ~ 6.1 blocks/CU; LDS chunks <= 24 KB so
//   6 blocks/CU fit; __launch_bounds__(128,3).
// - B stays fragment-packed + LDS-staged (ds_read pipe, zero bank conflicts).
// - SC steps/chunk chosen so SC*CC*MR == 12 for every layer (uniform preload).

typedef __bf16 bf16;
typedef bf16  bf16x4 __attribute__((ext_vector_type(4)));
typedef bf16  bf16x8 __attribute__((ext_vector_type(8)));
typedef float f32x4  __attribute__((ext_vector_type(4)));

// Pack W [K][COUT] f32 into fragment-ordered bf16:
// frag f = (s*CC + cc)*NT + t; element lane*8+j of frag f is
// W[k = s*CIN + cc*32 + (lane>>4)*8 + j][col = t*16 + (lane&15)].
template<int CIN, int COUT>
__device__ inline void pack_one(const float* __restrict__ W, bf16* __restrict__ BP, int e) {
    constexpr int NT = COUT / 16, CC = CIN / 32;
    const int f = e >> 9, r = e & 511, lane = r >> 3, j = r & 7;
    const int t = f % NT, cc = (f / NT) % CC, s = f / (NT * CC);
    const int col = t * 16 + (lane & 15);
    const int k   = s * CIN + cc * 32 + (lane >> 4) * 8 + j;
    BP[e] = (bf16)W[k * COUT + col];
}

__global__ __launch_bounds__(256)
void prep_all(const float* __restrict__ x, bf16* __restrict__ xb,
              const float* __restrict__ W0, const float* __restrict__ W1,
              const float* __restrict__ W2, bf16* __restrict__ B0,
              bf16* __restrict__ B1, bf16* __restrict__ B2, int n)
{
    const int gid = blockIdx.x * 256 + threadIdx.x;
    const int e = gid * 4;
    if (e < n * 32) {
        const f32x4 v = *reinterpret_cast<const f32x4*>(x + e);
        bf16x4 o = {(bf16)v[0], (bf16)v[1], (bf16)v[2], (bf16)v[3]};
        *reinterpret_cast<bf16x4*>(xb + e) = o;
    }
    if (gid < 384 * 64)                       pack_one<32, 64>(W0, B0, gid);
    else if (gid < 384 * 64 + 768 * 64)       pack_one<64, 64>(W1, B1, gid - 384 * 64);
    else if (gid < 384 * 64 + 768 * 64 + 768 * 32)
                                              pack_one<64, 32>(W2, B2, gid - 384 * 64 - 768 * 64);
}

template<int CIN, int COUT, bool ELU, typename TOUT>
__global__ __launch_bounds__(128, 3)
void spiral_mfma(const bf16* __restrict__ h, const int* __restrict__ idx,
                 const bf16* __restrict__ BP, const float* __restrict__ bias,
                 TOUT* __restrict__ out, int n)
{
    constexpr int CC  = CIN / 32;        // 32-k chunks per spiral step
    constexpr int NT  = COUT / 16;       // 16-col output tiles
    constexpr int PS  = CIN * COUT;      // B elems per spiral step
    constexpr int SC  = 6 / CC;          // steps/chunk: preload = SC*CC*2 = 12
    constexpr int NCH = 12 / SC;         // chunks per layer
    constexpr int PL  = SC * CC;         // preloads per tile per chunk (= 6)

    __shared__ bf16 Bs[SC * PS];         // 24 KB (L0/L1), 12 KB (L2)

    const int tid  = threadIdx.x;
    const int lane = tid & 63;
    const int wave = tid >> 6;           // 0..1
    const int m    = lane & 15;
    const int quad = lane >> 4;
    const int i0   = (blockIdx.x * 2 + wave) * 32;   // MR=2 tiles of 16 rows
    const bool valid = (i0 < n);                     // n%32==0: all-or-none

    // Prefetch both tiles' gather indices (48B/row, 16B-aligned), clamped.
    const int ir0 = min(i0 + m,      n - 1);
    const int ir1 = min(i0 + 16 + m, n - 1);
    const int4* p0 = reinterpret_cast<const int4*>(idx + (size_t)ir0 * 12);
    const int4* p1 = reinterpret_cast<const int4*>(idx + (size_t)ir1 * 12);
    const int4 q00 = p0[0], q01 = p0[1], q02 = p0[2];
    const int4 q10 = p1[0], q11 = p1[1], q12 = p1[2];
    const int rg0[12] = {q00.x,q00.y,q00.z,q00.w, q01.x,q01.y,q01.z,q01.w, q02.x,q02.y,q02.z,q02.w};
    const int rg1[12] = {q10.x,q10.y,q10.z,q10.w, q11.x,q11.y,q11.z,q11.w, q12.x,q12.y,q12.z,q12.w};

    f32x4 acc0[NT] = {}, acc1[NT] = {};

    #pragma unroll
    for (int c = 0; c < NCH; ++c) {
        if (c) __syncthreads();          // Bs reuse
        // Stage chunk c of packed B into LDS (contiguous 16B copies).
        const bf16* src = BP + (size_t)c * SC * PS;
        #pragma unroll
        for (int r2 = tid; r2 < SC * PS / 8; r2 += 128)
            *reinterpret_cast<bf16x8*>(&Bs[r2 * 8]) =
                *reinterpret_cast<const bf16x8*>(&src[r2 * 8]);
        __syncthreads();

        // --- A-preload: 12 independent gathers issued back-to-back ---
        bf16x8 a0[PL], a1[PL];
        #pragma unroll
        for (int sl = 0; sl < SC; ++sl) {
            const int s = c * SC + sl;
            #pragma unroll
            for (int cc = 0; cc < CC; ++cc) {
                const int co = cc * 32 + quad * 8;
                a0[sl * CC + cc] = *reinterpret_cast<const bf16x8*>(
                    h + (size_t)rg0[s] * CIN + co);
                a1[sl * CC + cc] = *reinterpret_cast<const bf16x8*>(
                    h + (size_t)rg1[s] * CIN + co);
            }
        }

        // --- MFMA over the chunk (B from LDS, A from registers) ---
        #pragma unroll
        for (int p = 0; p < PL; ++p) {
            #pragma unroll
            for (int t = 0; t < NT; ++t) {
                const bf16x8 b = *reinterpret_cast<const bf16x8*>(
                    &Bs[(p * NT + t) * 512 + lane * 8]);
                acc0[t] = __builtin_amdgcn_mfma_f32_16x16x32_bf16(a0[p], b, acc0[t], 0, 0, 0);
                acc1[t] = __builtin_amdgcn_mfma_f32_16x16x32_bf16(a1[p], b, acc1[t], 0, 0, 0);
            }
        }
    }

    if (!valid) return;

    // Epilogue: D[row = quad*4+g][col = t*16+m]; n%32==0 -> no row guards.
    #pragma unroll
    for (int t = 0; t < NT; ++t) {
        const int col = t * 16 + m;
        const float bv = bias[col];
        #pragma unroll
        for (int g = 0; g < 4; ++g) {
            {
                const int row = i0 + quad * 4 + g;
                float v = acc0[t][g] + bv;
                if (ELU) v = (v > 0.f) ? v : (__expf(v) - 1.f);
                out[(size_t)row * COUT + col] = (TOUT)v;
            }
            {
                const int row = i0 + 16 + quad * 4 + g;
                float v = acc1[t][g] + bv;
                if (ELU) v = (v > 0.f) ? v : (__expf(v) - 1.f);
                out[(size_t)row * COUT + col] = (TOUT)v;
            }
        }
    }
}

extern "C" void kernel_launch(void* const* d_in, const int* in_sizes, int n_in,
                              void* d_out, int out_size, void* d_ws, size_t ws_size,
                              hipStream_t stream) {
    const float* x   = (const float*)d_in[0];   // [N,32] fp32
    const int*   idx = (const int*)d_in[1];     // [N,12]
    const float* W0  = (const float*)d_in[2];   // [384,64]
    const float* b0  = (const float*)d_in[3];
    const float* W1  = (const float*)d_in[4];   // [768,64]
    const float* b1  = (const float*)d_in[5];
    const float* W2  = (const float*)d_in[6];   // [768,32]
    const float* b2  = (const float*)d_in[7];
    float* out = (float*)d_out;                 // [N,32] fp32

    const int n = in_sizes[0] / 32;             // N = 100000

    bf16* xb = (bf16*)d_ws;                     // [n,32]
    bf16* h1 = xb + (size_t)n * 32;             // [n,64]
    bf16* h2 = h1 + (size_t)n * 64;             // [n,64]
    bf16* B0 = h2 + (size_t)n * 64;             // 384*64
    bf16* B1 = B0 + 384 * 64;                   // 768*64
    bf16* B2 = B1 + 768 * 64;                   // 768*32

    const int prep_threads = n * 8;             // covers n*32/4 cvt + 98304 pack
    prep_all<<<(prep_threads + 255) / 256, dim3(256), 0, stream>>>(x, xb, W0, W1, W2, B0, B1, B2, n);

    const int grid = (n + 63) / 64;             // 2 waves x 32 rows per block
    spiral_mfma<32, 64, true,  bf16 ><<<grid, dim3(128), 0, stream>>>(xb, idx, B0, b0, h1,  n);
    spiral_mfma<64, 64, true,  bf16 ><<<grid, dim3(128), 0, stream>>>(h1, idx, B1, b1, h2,  n);
    spiral_mfma<64, 32, false, float><<<grid, dim3(128), 0, stream>>>(h2, idx, B2, b2, out, n);
}

// Round 7
// 169.418 us; speedup vs baseline: 1.1069x; 1.1069x over previous
//
#include <hip/hip_runtime.h>
#include <math.h>

// SpiralNet bf16-MFMA v7.
// vs R6: the 12-deep gather batch is made UNBREAKABLE. R6's VGPR_Count=68 proved
// the compiler re-serialized the preload (needs >=80 regs). Fixes:
//  - __launch_bounds__(256,3) -> 170-VGPR cap, structure peaks ~120.
//  - __builtin_amdgcn_sched_barrier(0) after each gather batch: loads cannot
//    sink into the MFMA loop.
//  - per 48KB B-chunk: stage->barrier->[12 gathers t0|fence|48 MFMA]->[t1 ...].
//  - block=256 (4 waves, MR=2, 128 rows), grid 782 ~ 3 blocks/CU = 12 waves/CU;
//    B-restage misses ~2.3K/CU; LDS-B pipe ~14K cyc/CU stays sub-dominant.

typedef __bf16 bf16;
typedef bf16  bf16x4 __attribute__((ext_vector_type(4)));
typedef bf16  bf16x8 __attribute__((ext_vector_type(8)));
typedef float f32x4  __attribute__((ext_vector_type(4)));

// Pack W [K][COUT] f32 into fragment-ordered bf16:
// frag f = (s*CC + cc)*NT + t; element lane*8+j of frag f is
// W[k = s*CIN + cc*32 + (lane>>4)*8 + j][col = t*16 + (lane&15)].
template<int CIN, int COUT>
__device__ inline void pack_one(const float* __restrict__ W, bf16* __restrict__ BP, int e) {
    constexpr int NT = COUT / 16, CC = CIN / 32;
    const int f = e >> 9, r = e & 511, lane = r >> 3, j = r & 7;
    const int t = f % NT, cc = (f / NT) % CC, s = f / (NT * CC);
    const int col = t * 16 + (lane & 15);
    const int k   = s * CIN + cc * 32 + (lane >> 4) * 8 + j;
    BP[e] = (bf16)W[k * COUT + col];
}

__global__ __launch_bounds__(256)
void prep_all(const float* __restrict__ x, bf16* __restrict__ xb,
              const float* __restrict__ W0, const float* __restrict__ W1,
              const float* __restrict__ W2, bf16* __restrict__ B0,
              bf16* __restrict__ B1, bf16* __restrict__ B2, int n)
{
    const int gid = blockIdx.x * 256 + threadIdx.x;
    const int e = gid * 4;
    if (e < n * 32) {
        const f32x4 v = *reinterpret_cast<const f32x4*>(x + e);
        bf16x4 o = {(bf16)v[0], (bf16)v[1], (bf16)v[2], (bf16)v[3]};
        *reinterpret_cast<bf16x4*>(xb + e) = o;
    }
    if (gid < 384 * 64)                       pack_one<32, 64>(W0, B0, gid);
    else if (gid < 384 * 64 + 768 * 64)       pack_one<64, 64>(W1, B1, gid - 384 * 64);
    else if (gid < 384 * 64 + 768 * 64 + 768 * 32)
                                              pack_one<64, 32>(W2, B2, gid - 384 * 64 - 768 * 64);
}

template<int CIN, int COUT, bool ELU, typename TOUT>
__global__ __launch_bounds__(256, 3)
void spiral_mfma(const bf16* __restrict__ h, const int* __restrict__ idx,
                 const bf16* __restrict__ BP, const float* __restrict__ bias,
                 TOUT* __restrict__ out, int n)
{
    constexpr int CC  = CIN / 32;        // 32-k chunks per spiral step (1 or 2)
    constexpr int NT  = COUT / 16;       // 16-col output tiles (2 or 4)
    constexpr int PS  = CIN * COUT;      // B elems per spiral step
    constexpr int SC  = 12 / CC;         // steps per chunk -> PL = SC*CC = 12 always
    constexpr int NCH = 12 / SC;         // chunks per layer (1 or 2)
    constexpr int PL  = 12;              // gathers per tile per chunk

    __shared__ bf16 Bs[SC * PS];         // 48 KB (L0/L1), 24 KB (L2)

    const int tid  = threadIdx.x;
    const int lane = tid & 63;
    const int wave = tid >> 6;           // 0..3
    const int m    = lane & 15;
    const int quad = lane >> 4;
    const int i0   = (blockIdx.x * 4 + wave) * 32;   // MR=2 tiles of 16 rows
    const bool valid = (i0 < n);                     // n%32==0: all-or-none

    // Gather indices for both tiles (48B/row, 16B-aligned), clamped for
    // out-of-range waves (they compute garbage but skip the epilogue).
    const int ir0 = min(i0 + m,      n - 1);
    const int ir1 = min(i0 + 16 + m, n - 1);
    const int4* p0 = reinterpret_cast<const int4*>(idx + (size_t)ir0 * 12);
    const int4* p1 = reinterpret_cast<const int4*>(idx + (size_t)ir1 * 12);
    const int4 q00 = p0[0], q01 = p0[1], q02 = p0[2];
    const int4 q10 = p1[0], q11 = p1[1], q12 = p1[2];
    const int rg0[12] = {q00.x,q00.y,q00.z,q00.w, q01.x,q01.y,q01.z,q01.w, q02.x,q02.y,q02.z,q02.w};
    const int rg1[12] = {q10.x,q10.y,q10.z,q10.w, q11.x,q11.y,q11.z,q11.w, q12.x,q12.y,q12.z,q12.w};

    f32x4 acc0[NT] = {}, acc1[NT] = {};

    #pragma unroll
    for (int c = 0; c < NCH; ++c) {
        if (c) __syncthreads();          // Bs reuse: consumers done
        // Stage chunk c of packed B into LDS (contiguous 16B copies).
        const bf16* src = BP + (size_t)c * SC * PS;
        #pragma unroll
        for (int r2 = tid; r2 < SC * PS / 8; r2 += 256)
            *reinterpret_cast<bf16x8*>(&Bs[r2 * 8]) =
                *reinterpret_cast<const bf16x8*>(&src[r2 * 8]);
        __syncthreads();

        // ---- tile 0: 12 independent gathers, fenced, then 12*NT MFMAs ----
        {
            bf16x8 a[PL];
            #pragma unroll
            for (int sl = 0; sl < SC; ++sl)
                #pragma unroll
                for (int cc = 0; cc < CC; ++cc)
                    a[sl * CC + cc] = *reinterpret_cast<const bf16x8*>(
                        h + (size_t)rg0[c * SC + sl] * CIN + cc * 32 + quad * 8);
            __builtin_amdgcn_sched_barrier(0);   // loads must all issue first
            #pragma unroll
            for (int p = 0; p < PL; ++p)
                #pragma unroll
                for (int t = 0; t < NT; ++t) {
                    const bf16x8 b = *reinterpret_cast<const bf16x8*>(
                        &Bs[(p * NT + t) * 512 + lane * 8]);
                    acc0[t] = __builtin_amdgcn_mfma_f32_16x16x32_bf16(a[p], b, acc0[t], 0, 0, 0);
                }
        }
        // ---- tile 1 ----
        {
            bf16x8 a[PL];
            #pragma unroll
            for (int sl = 0; sl < SC; ++sl)
                #pragma unroll
                for (int cc = 0; cc < CC; ++cc)
                    a[sl * CC + cc] = *reinterpret_cast<const bf16x8*>(
                        h + (size_t)rg1[c * SC + sl] * CIN + cc * 32 + quad * 8);
            __builtin_amdgcn_sched_barrier(0);
            #pragma unroll
            for (int p = 0; p < PL; ++p)
                #pragma unroll
                for (int t = 0; t < NT; ++t) {
                    const bf16x8 b = *reinterpret_cast<const bf16x8*>(
                        &Bs[(p * NT + t) * 512 + lane * 8]);
                    acc1[t] = __builtin_amdgcn_mfma_f32_16x16x32_bf16(a[p], b, acc1[t], 0, 0, 0);
                }
        }
    }

    if (!valid) return;

    // Epilogue: D[row = quad*4+g][col = t*16+m]; n%32==0 -> no row guards.
    #pragma unroll
    for (int t = 0; t < NT; ++t) {
        const int col = t * 16 + m;
        const float bv = bias[col];
        #pragma unroll
        for (int g = 0; g < 4; ++g) {
            {
                const int row = i0 + quad * 4 + g;
                float v = acc0[t][g] + bv;
                if (ELU) v = (v > 0.f) ? v : (__expf(v) - 1.f);
                out[(size_t)row * COUT + col] = (TOUT)v;
            }
            {
                const int row = i0 + 16 + quad * 4 + g;
                float v = acc1[t][g] + bv;
                if (ELU) v = (v > 0.f) ? v : (__expf(v) - 1.f);
                out[(size_t)row * COUT + col] = (TOUT)v;
            }
        }
    }
}

extern "C" void kernel_launch(void* const* d_in, const int* in_sizes, int n_in,
                              void* d_out, int out_size, void* d_ws, size_t ws_size,
                              hipStream_t stream) {
    const float* x   = (const float*)d_in[0];   // [N,32] fp32
    const int*   idx = (const int*)d_in[1];     // [N,12]
    const float* W0  = (const float*)d_in[2];   // [384,64]
    const float* b0  = (const float*)d_in[3];
    const float* W1  = (const float*)d_in[4];   // [768,64]
    const float* b1  = (const float*)d_in[5];
    const float* W2  = (const float*)d_in[6];   // [768,32]
    const float* b2  = (const float*)d_in[7];
    float* out = (float*)d_out;                 // [N,32] fp32

    const int n = in_sizes[0] / 32;             // N = 100000

    bf16* xb = (bf16*)d_ws;                     // [n,32]
    bf16* h1 = xb + (size_t)n * 32;             // [n,64]
    bf16* h2 = h1 + (size_t)n * 64;             // [n,64]
    bf16* B0 = h2 + (size_t)n * 64;             // 384*64
    bf16* B1 = B0 + 384 * 64;                   // 768*64
    bf16* B2 = B1 + 768 * 64;                   // 768*32

    const int prep_threads = n * 8;             // covers n*32/4 cvt + 98304 pack
    prep_all<<<(prep_threads + 255) / 256, dim3(256), 0, stream>>>(x, xb, W0, W1, W2, B0, B1, B2, n);

    const int grid = (n + 127) / 128;           // 4 waves x (2x16) rows per block
    spiral_mfma<32, 64, true,  bf16 ><<<grid, dim3(256), 0, stream>>>(xb, idx, B0, b0, h1,  n);
    spiral_mfma<64, 64, true,  bf16 ><<<grid, dim3(256), 0, stream>>>(h1, idx, B1, b1, h2,  n);
    spiral_mfma<64, 32, false, float><<<grid, dim3(256), 0, stream>>>(h2, idx, B2, b2, out, n);
}

// Round 8
// 157.759 us; speedup vs baseline: 1.1887x; 1.0739x over previous
//
#include <hip/hip_runtime.h>
#include <math.h>

// SpiralNet bf16-MFMA v8: concurrency experiment.
// Five structurally different kernels (R2,R4-R7) all land 169-190 us -> the
// invariant is random-gather latency x concurrency. This version maximizes
// OFFERED concurrency: 20 waves/CU x fenced depth-6 batches = 120 outstanding
// gathers/CU (vs ~40 before).
//  - MR=1: 16 rows/wave, grid 1563 ~ 6.1 blocks/CU.
//  - __launch_bounds__(256,5): VGPR cap 102 (need ~75) -> 5 blocks/CU resident.
//  - LDS B chunks <= 24 KB (SC=6/CC) -> 5 x 24 KB = 120 KB <= 160 KB.
//  - sched_barrier(0) pins each 6-gather batch ahead of its MFMA block.
// If this stays ~170 us, the per-CU outstanding-miss cap (~48) is confirmed
// as the structural floor for this gather pattern.

typedef __bf16 bf16;
typedef bf16  bf16x4 __attribute__((ext_vector_type(4)));
typedef bf16  bf16x8 __attribute__((ext_vector_type(8)));
typedef float f32x4  __attribute__((ext_vector_type(4)));

// Pack W [K][COUT] f32 into fragment-ordered bf16:
// frag f = (s*CC + cc)*NT + t; element lane*8+j of frag f is
// W[k = s*CIN + cc*32 + (lane>>4)*8 + j][col = t*16 + (lane&15)].
template<int CIN, int COUT>
__device__ inline void pack_one(const float* __restrict__ W, bf16* __restrict__ BP, int e) {
    constexpr int NT = COUT / 16, CC = CIN / 32;
    const int f = e >> 9, r = e & 511, lane = r >> 3, j = r & 7;
    const int t = f % NT, cc = (f / NT) % CC, s = f / (NT * CC);
    const int col = t * 16 + (lane & 15);
    const int k   = s * CIN + cc * 32 + (lane >> 4) * 8 + j;
    BP[e] = (bf16)W[k * COUT + col];
}

__global__ __launch_bounds__(256)
void prep_all(const float* __restrict__ x, bf16* __restrict__ xb,
              const float* __restrict__ W0, const float* __restrict__ W1,
              const float* __restrict__ W2, bf16* __restrict__ B0,
              bf16* __restrict__ B1, bf16* __restrict__ B2, int n)
{
    const int gid = blockIdx.x * 256 + threadIdx.x;
    const int e = gid * 4;
    if (e < n * 32) {
        const f32x4 v = *reinterpret_cast<const f32x4*>(x + e);
        bf16x4 o = {(bf16)v[0], (bf16)v[1], (bf16)v[2], (bf16)v[3]};
        *reinterpret_cast<bf16x4*>(xb + e) = o;
    }
    if (gid < 384 * 64)                       pack_one<32, 64>(W0, B0, gid);
    else if (gid < 384 * 64 + 768 * 64)       pack_one<64, 64>(W1, B1, gid - 384 * 64);
    else if (gid < 384 * 64 + 768 * 64 + 768 * 32)
                                              pack_one<64, 32>(W2, B2, gid - 384 * 64 - 768 * 64);
}

template<int CIN, int COUT, bool ELU, typename TOUT>
__global__ __launch_bounds__(256, 5)
void spiral_mfma(const bf16* __restrict__ h, const int* __restrict__ idx,
                 const bf16* __restrict__ BP, const float* __restrict__ bias,
                 TOUT* __restrict__ out, int n)
{
    constexpr int CC  = CIN / 32;        // 32-k chunks per spiral step (1 or 2)
    constexpr int NT  = COUT / 16;       // 16-col output tiles (2 or 4)
    constexpr int PS  = CIN * COUT;      // B elems per spiral step
    constexpr int SC  = 6 / CC;          // steps/chunk -> batch depth SC*CC = 6
    constexpr int NCH = 12 / SC;         // chunks per layer (2 or 4)
    constexpr int PL  = 6;               // fenced gathers per chunk per wave

    __shared__ bf16 Bs[SC * PS];         // 24 KB (L0/L1), 12 KB (L2)

    const int tid  = threadIdx.x;
    const int lane = tid & 63;
    const int wave = tid >> 6;           // 0..3
    const int m    = lane & 15;
    const int quad = lane >> 4;
    const int i0   = (blockIdx.x * 4 + wave) * 16;   // MR=1: one 16-row tile
    const bool valid = (i0 < n);                     // n%16==0: all-or-none

    // Gather indices (48B/row, 16B-aligned), clamped for tail waves.
    const int ir = min(i0 + m, n - 1);
    const int4* ip = reinterpret_cast<const int4*>(idx + (size_t)ir * 12);
    const int4 q0 = ip[0], q1 = ip[1], q2 = ip[2];
    const int rg[12] = {q0.x,q0.y,q0.z,q0.w, q1.x,q1.y,q1.z,q1.w, q2.x,q2.y,q2.z,q2.w};

    f32x4 acc[NT] = {};

    #pragma unroll
    for (int c = 0; c < NCH; ++c) {
        if (c) __syncthreads();          // Bs reuse: consumers done
        // Stage chunk c of packed B into LDS (contiguous 16B copies).
        const bf16* src = BP + (size_t)c * SC * PS;
        #pragma unroll
        for (int r2 = tid; r2 < SC * PS / 8; r2 += 256)
            *reinterpret_cast<bf16x8*>(&Bs[r2 * 8]) =
                *reinterpret_cast<const bf16x8*>(&src[r2 * 8]);
        __syncthreads();

        // ---- fenced batch: 6 independent gathers, then 6*NT MFMAs ----
        bf16x8 a[PL];
        #pragma unroll
        for (int sl = 0; sl < SC; ++sl)
            #pragma unroll
            for (int cc = 0; cc < CC; ++cc)
                a[sl * CC + cc] = *reinterpret_cast<const bf16x8*>(
                    h + (size_t)rg[c * SC + sl] * CIN + cc * 32 + quad * 8);
        __builtin_amdgcn_sched_barrier(0);   // all 6 loads issue before MFMAs
        #pragma unroll
        for (int p = 0; p < PL; ++p)
            #pragma unroll
            for (int t = 0; t < NT; ++t) {
                const bf16x8 b = *reinterpret_cast<const bf16x8*>(
                    &Bs[(p * NT + t) * 512 + lane * 8]);
                acc[t] = __builtin_amdgcn_mfma_f32_16x16x32_bf16(a[p], b, acc[t], 0, 0, 0);
            }
    }

    if (!valid) return;

    // Epilogue: D[row = quad*4+g][col = t*16+m]; n%16==0 -> no row guards.
    #pragma unroll
    for (int t = 0; t < NT; ++t) {
        const int col = t * 16 + m;
        const float bv = bias[col];
        #pragma unroll
        for (int g = 0; g < 4; ++g) {
            const int row = i0 + quad * 4 + g;
            float v = acc[t][g] + bv;
            if (ELU) v = (v > 0.f) ? v : (__expf(v) - 1.f);
            out[(size_t)row * COUT + col] = (TOUT)v;
        }
    }
}

extern "C" void kernel_launch(void* const* d_in, const int* in_sizes, int n_in,
                              void* d_out, int out_size, void* d_ws, size_t ws_size,
                              hipStream_t stream) {
    const float* x   = (const float*)d_in[0];   // [N,32] fp32
    const int*   idx = (const int*)d_in[1];     // [N,12]
    const float* W0  = (const float*)d_in[2];   // [384,64]
    const float* b0  = (const float*)d_in[3];
    const float* W1  = (const float*)d_in[4];   // [768,64]
    const float* b1  = (const float*)d_in[5];
    const float* W2  = (const float*)d_in[6];   // [768,32]
    const float* b2  = (const float*)d_in[7];
    float* out = (float*)d_out;                 // [N,32] fp32

    const int n = in_sizes[0] / 32;             // N = 100000

    bf16* xb = (bf16*)d_ws;                     // [n,32]
    bf16* h1 = xb + (size_t)n * 32;             // [n,64]
    bf16* h2 = h1 + (size_t)n * 64;             // [n,64]
    bf16* B0 = h2 + (size_t)n * 64;             // 384*64
    bf16* B1 = B0 + 384 * 64;                   // 768*64
    bf16* B2 = B1 + 768 * 64;                   // 768*32

    const int prep_threads = n * 8;             // covers n*32/4 cvt + 98304 pack
    prep_all<<<(prep_threads + 255) / 256, dim3(256), 0, stream>>>(x, xb, W0, W1, W2, B0, B1, B2, n);

    const int grid = (n + 63) / 64;             // 4 waves x 16 rows per block
    spiral_mfma<32, 64, true,  bf16 ><<<grid, dim3(256), 0, stream>>>(xb, idx, B0, b0, h1,  n);
    spiral_mfma<64, 64, true,  bf16 ><<<grid, dim3(256), 0, stream>>>(h1, idx, B1, b1, h2,  n);
    spiral_mfma<64, 32, false, float><<<grid, dim3(256), 0, stream>>>(h2, idx, B2, b2, out, n);
}